// Round 1
// baseline (153.288 us; speedup 1.0000x reference)
//
#include <hip/hip_runtime.h>
#include <math.h>

#define N_IMG 32
#define L_ROI 4096
#define M_GT  128
#define C_CLS 80
#define IOU_T 0.5f

// ---------------------------------------------------------------------------
// K1: per-roi IoU match vs all gt boxes (staged in LDS).
//     Writes lp[n*L+l] = pos ? label : -1, zeroes nll_arr, counts n_pos[n].
// ---------------------------------------------------------------------------
__global__ __launch_bounds__(256) void k_match(
    const float* __restrict__ rois,      // [N,L,4]
    const float* __restrict__ gt_boxes,  // [N,M,4]
    const int*   __restrict__ gt_cls,    // [N,M]
    int*   __restrict__ lp,              // [N,L] label-or-neg1
    float* __restrict__ nll_arr,         // [N,L] zeroed here
    int*   __restrict__ n_pos)           // [N]
{
    __shared__ float4 sgt[M_GT];
    __shared__ float  sarea[M_GT];
    __shared__ int    scount;

    const int n    = blockIdx.x >> 4;          // 16 blocks per image (4096/256)
    const int lblk = (blockIdx.x & 15) * 256;
    const int t    = threadIdx.x;
    if (t == 0) scount = 0;
    if (t < M_GT) {
        float4 g = ((const float4*)gt_boxes)[n * M_GT + t];
        sgt[t]   = g;
        sarea[t] = (g.z - g.x) * (g.w - g.y);
    }
    __syncthreads();

    const int l = lblk + t;
    float4 r = ((const float4*)rois)[(size_t)n * L_ROI + l];
    float ar = (r.z - r.x) * (r.w - r.y);

    float best = -1.0f;
    int   bi   = 0;
    #pragma unroll 4
    for (int m = 0; m < M_GT; ++m) {
        float4 g = sgt[m];
        float ix = fminf(r.z, g.z) - fmaxf(r.x, g.x);
        float iy = fminf(r.w, g.w) - fmaxf(r.y, g.y);
        ix = fmaxf(ix, 0.0f);
        iy = fmaxf(iy, 0.0f);
        float inter = ix * iy;
        float iou   = inter / (ar + sarea[m] - inter);
        if (iou > best) { best = iou; bi = m; }   // strict >: first-occurrence argmax
    }
    const int pos = (best >= IOU_T) ? 1 : 0;
    const int lab = gt_cls[n * M_GT + bi];

    lp[(size_t)n * L_ROI + l]      = pos ? lab : -1;
    nll_arr[(size_t)n * L_ROI + l] = 0.0f;

    unsigned long long mask = __ballot(pos);
    if ((t & 63) == 0) atomicAdd(&scount, (int)__popcll(mask));
    __syncthreads();
    if (t == 0) atomicAdd(&n_pos[n], scount);
}

// ---------------------------------------------------------------------------
// K2: one wavefront per (image, class): keep first sample_num positives of
//     that class in roi-index order (matches cumsum-rank semantics).
//     Appends selected roi ids to a compact list.
// ---------------------------------------------------------------------------
__global__ __launch_bounds__(256) void k_select(
    const int* __restrict__ lp,
    const int* __restrict__ n_pos,
    int* __restrict__ sel_count,     // [1]
    int* __restrict__ sel_cnt_img,   // [N]
    int* __restrict__ list)          // capacity N*L
{
    const int wid = (blockIdx.x << 2) + (threadIdx.x >> 6);
    if (wid >= N_IMG * C_CLS) return;
    const int n = wid / C_CLS;
    const int c = wid % C_CLS;

    const int np = n_pos[n];
    const int sn = max(1, (np + C_CLS - 1) / C_CLS);   // ceil(max(1, np/C))

    const int lane = threadIdx.x & 63;
    const int* row = lp + (size_t)n * L_ROI;
    int count = 0;
    for (int base = 0; base < L_ROI; base += 64) {
        const int m = (row[base + lane] == c) ? 1 : 0;
        unsigned long long mask = __ballot(m);
        if (m) {
            int prefix = (int)__popcll(mask & ((1ull << lane) - 1ull));
            if (count + prefix < sn) {
                int idx = atomicAdd(sel_count, 1);
                list[idx] = (n << 12) | (base + lane);
                atomicAdd(&sel_cnt_img[n], 1);
            }
        }
        count += (int)__popcll(mask);
        if (count >= sn) break;   // wave-uniform (ballot-derived)
    }
}

// ---------------------------------------------------------------------------
// K3: one wavefront per selected roi: 80-class logsumexp + nll write.
//     Grid-stride over the device-side list.
// ---------------------------------------------------------------------------
__global__ __launch_bounds__(256) void k_nll(
    const float* __restrict__ cls_scores,  // [N,L,C]
    const int*   __restrict__ lp,
    const int*   __restrict__ sel_count,
    const int*   __restrict__ list,
    float* __restrict__ nll_arr)
{
    const int nw   = (gridDim.x * blockDim.x) >> 6;
    const int wid  = (blockIdx.x * blockDim.x + threadIdx.x) >> 6;
    const int lane = threadIdx.x & 63;
    const int cnt  = *sel_count;

    for (int i = wid; i < cnt; i += nw) {
        const int e = list[i];
        const int n = e >> 12;
        const int l = e & 4095;
        const float* row = cls_scores + ((size_t)n * L_ROI + l) * C_CLS;

        float v0 = row[lane];
        float v1 = (lane < C_CLS - 64) ? row[64 + lane] : -INFINITY;
        float mx = fmaxf(v0, v1);
        #pragma unroll
        for (int o = 32; o; o >>= 1) mx = fmaxf(mx, __shfl_xor(mx, o));
        float s = expf(v0 - mx) + ((lane < C_CLS - 64) ? expf(v1 - mx) : 0.0f);
        #pragma unroll
        for (int o = 32; o; o >>= 1) s += __shfl_xor(s, o);

        if (lane == 0) {
            int   lab  = lp[(size_t)n * L_ROI + l];
            float logZ = mx + logf(s);
            nll_arr[(size_t)n * L_ROI + l] = logZ - row[lab];
        }
    }
}

// ---------------------------------------------------------------------------
// K4: per-image fixed-order reduction of nll_arr -> per_img[n]
// ---------------------------------------------------------------------------
__global__ __launch_bounds__(256) void k_img_reduce(
    const float* __restrict__ nll_arr,
    const int*   __restrict__ sel_cnt_img,
    float* __restrict__ per_img)
{
    __shared__ float sdata[256];
    const int n = blockIdx.x;
    const int t = threadIdx.x;
    const float* row = nll_arr + (size_t)n * L_ROI;
    float s = 0.0f;
    for (int i = t; i < L_ROI; i += 256) s += row[i];
    sdata[t] = s;
    __syncthreads();
    for (int o = 128; o; o >>= 1) {
        if (t < o) sdata[t] += sdata[t + o];
        __syncthreads();
    }
    if (t == 0) per_img[n] = sdata[0] / (float)sel_cnt_img[n];
}

// ---------------------------------------------------------------------------
// K5: sum 32 per-image losses -> out[0]
// ---------------------------------------------------------------------------
__global__ void k_final(const float* __restrict__ per_img, float* __restrict__ out)
{
    const int lane = threadIdx.x;
    float v = (lane < N_IMG) ? per_img[lane] : 0.0f;
    #pragma unroll
    for (int o = 32; o; o >>= 1) v += __shfl_xor(v, o);
    if (lane == 0) out[0] = v;
}

extern "C" void kernel_launch(void* const* d_in, const int* in_sizes, int n_in,
                              void* d_out, int out_size, void* d_ws, size_t ws_size,
                              hipStream_t stream) {
    const float* rois       = (const float*)d_in[0];
    const float* cls_scores = (const float*)d_in[1];
    // d_in[2] = bbox_deltas: only feeds 0.0 * chosen.sum() -> never read.
    const float* gt_boxes   = (const float*)d_in[3];
    const int*   gt_clses   = (const int*)d_in[4];
    float* out = (float*)d_out;

    char* ws = (char*)d_ws;
    int*   n_pos       = (int*)(ws + 0);              // 32 ints
    int*   sel_cnt_img = (int*)(ws + 128);            // 32 ints
    int*   sel_count   = (int*)(ws + 256);            // 1 int
    float* per_img     = (float*)(ws + 320);          // 32 floats
    int*   lp          = (int*)(ws + 512);            // N*L ints
    float* nll_arr     = (float*)(ws + 512 + 524288); // N*L floats
    int*   list        = (int*)(ws + 512 + 2*524288); // N*L ints

    hipMemsetAsync(d_ws, 0, 512, stream);  // zero counters + per_img

    k_match<<<N_IMG * (L_ROI / 256), 256, 0, stream>>>(
        rois, gt_boxes, gt_clses, lp, nll_arr, n_pos);
    k_select<<<(N_IMG * C_CLS + 3) / 4, 256, 0, stream>>>(
        lp, n_pos, sel_count, sel_cnt_img, list);
    k_nll<<<128, 256, 0, stream>>>(cls_scores, lp, sel_count, list, nll_arr);
    k_img_reduce<<<N_IMG, 256, 0, stream>>>(nll_arr, sel_cnt_img, per_img);
    k_final<<<1, 64, 0, stream>>>(per_img, out);
}

// Round 2
// 56.023 us; speedup vs baseline: 2.7362x; 2.7362x over previous
//
#include <hip/hip_runtime.h>
#include <math.h>

#define N_IMG 32
#define L_ROI 4096
#define M_GT  128
#define C_CLS 80
#define IOU_T 0.5f

// ---------------------------------------------------------------------------
// K1: per-roi IoU match vs all gt boxes (staged in LDS).
//     Writes lp[n*L+l] = pos ? label : -1.
// ---------------------------------------------------------------------------
__global__ __launch_bounds__(256) void k_match(
    const float* __restrict__ rois,      // [N,L,4]
    const float* __restrict__ gt_boxes,  // [N,M,4]
    const int*   __restrict__ gt_cls,    // [N,M]
    int*   __restrict__ lp)              // [N,L] label-or-neg1
{
    __shared__ float4 sgt[M_GT];
    __shared__ float  sarea[M_GT];

    const int n    = blockIdx.x >> 4;          // 16 blocks per image (4096/256)
    const int lblk = (blockIdx.x & 15) * 256;
    const int t    = threadIdx.x;
    if (t < M_GT) {
        float4 g = ((const float4*)gt_boxes)[n * M_GT + t];
        sgt[t]   = g;
        sarea[t] = (g.z - g.x) * (g.w - g.y);
    }
    __syncthreads();

    const int l = lblk + t;
    float4 r = ((const float4*)rois)[(size_t)n * L_ROI + l];
    float ar = (r.z - r.x) * (r.w - r.y);

    float best = -1.0f;
    int   bi   = 0;
    #pragma unroll 4
    for (int m = 0; m < M_GT; ++m) {
        float4 g = sgt[m];
        float ix = fminf(r.z, g.z) - fmaxf(r.x, g.x);
        float iy = fminf(r.w, g.w) - fmaxf(r.y, g.y);
        ix = fmaxf(ix, 0.0f);
        iy = fmaxf(iy, 0.0f);
        float inter = ix * iy;
        float iou   = inter / (ar + sarea[m] - inter);
        if (iou > best) { best = iou; bi = m; }   // strict >: first-occurrence argmax
    }
    const int pos = (best >= IOU_T) ? 1 : 0;
    const int lab = gt_cls[n * M_GT + bi];
    lp[(size_t)n * L_ROI + l] = pos ? lab : -1;
}

// ---------------------------------------------------------------------------
// K2: one block per image: ordered compaction of positives into
//     plist[n][i] = (roi_idx << 7) | label, i in roi-index order.
// ---------------------------------------------------------------------------
__global__ __launch_bounds__(256) void k_compact(
    const int* __restrict__ lp,
    int* __restrict__ plist,      // [N,L] packed
    int* __restrict__ np_arr)     // [N]
{
    __shared__ int swt[4];
    const int n    = blockIdx.x;
    const int t    = threadIdx.x;
    const int lane = t & 63;
    const int wv   = t >> 6;
    const int* row = lp + (size_t)n * L_ROI;
    int* out       = plist + (size_t)n * L_ROI;

    int base = 0;
    for (int chunk = 0; chunk < L_ROI; chunk += 256) {
        const int lab = row[chunk + t];
        const int p   = (lab >= 0) ? 1 : 0;
        unsigned long long mask = __ballot(p);
        int wpref = (int)__popcll(mask & ((1ull << lane) - 1ull));
        if (lane == 0) swt[wv] = (int)__popcll(mask);
        __syncthreads();
        int woff = 0;
        for (int w = 0; w < wv; ++w) woff += swt[w];
        const int total = swt[0] + swt[1] + swt[2] + swt[3];
        if (p) out[base + woff + wpref] = ((chunk + t) << 7) | lab;
        base += total;
        __syncthreads();
    }
    if (t == 0) np_arr[n] = base;
}

// ---------------------------------------------------------------------------
// K3: one wave per (image, class): take first sn positives of class c in
//     roi order from the compact list; full wave computes each 80-class
//     logsumexp; writes private (n,c) slots — no atomics, no memset needed.
// ---------------------------------------------------------------------------
__global__ __launch_bounds__(256) void k_selnll(
    const float* __restrict__ cls_scores,  // [N,L,C]
    const int*   __restrict__ plist,
    const int*   __restrict__ np_arr,
    float* __restrict__ nllsum,            // [N*C]
    int*   __restrict__ selcnt)            // [N*C]
{
    const int wid  = (blockIdx.x << 2) + (threadIdx.x >> 6);   // exactly N*C waves
    const int n    = wid / C_CLS;
    const int c    = wid % C_CLS;
    const int lane = threadIdx.x & 63;

    const int np = np_arr[n];
    const int sn = max(1, (np + C_CLS - 1) / C_CLS);  // ceil(max(1, np/C))
    const int* pl = plist + (size_t)n * L_ROI;

    float lsum = 0.0f;
    int taken  = 0;
    for (int base = 0; base < np && taken < sn; base += 64) {
        const int e   = (base + lane < np) ? pl[base + lane] : -1;
        const int lab = e & 127;
        const int idx = e >> 7;
        unsigned long long mask = __ballot(e >= 0 && lab == c);
        const int take = min((int)__popcll(mask), sn - taken);
        unsigned long long mm = mask;
        for (int k = 0; k < take; ++k) {
            const int src = __ffsll((unsigned long long)mm) - 1;
            mm &= mm - 1;
            const int sidx = __shfl(idx, src);
            const int slab = __shfl(lab, src);
            const float* rp = cls_scores + ((size_t)n * L_ROI + sidx) * C_CLS;
            float v0 = rp[lane];
            float v1 = (lane < C_CLS - 64) ? rp[64 + lane] : -INFINITY;
            float mx = fmaxf(v0, v1);
            #pragma unroll
            for (int o = 32; o; o >>= 1) mx = fmaxf(mx, __shfl_xor(mx, o));
            float s = expf(v0 - mx) + ((lane < C_CLS - 64) ? expf(v1 - mx) : 0.0f);
            #pragma unroll
            for (int o = 32; o; o >>= 1) s += __shfl_xor(s, o);
            const float logZ = mx + logf(s);
            const float sc = (slab < 64) ? __shfl(v0, slab) : __shfl(v1, slab - 64);
            lsum += logZ - sc;
        }
        taken += take;
    }
    if (lane == 0) { nllsum[wid] = lsum; selcnt[wid] = taken; }
}

// ---------------------------------------------------------------------------
// K4: single wave: per-image mean over the 80 class slots, sum over images.
// ---------------------------------------------------------------------------
__global__ void k_final(const float* __restrict__ nllsum,
                        const int*   __restrict__ selcnt,
                        float* __restrict__ out)
{
    const int lane = threadIdx.x;   // 64 threads
    float tot = 0.0f;
    for (int n = 0; n < N_IMG; ++n) {
        float v = nllsum[n * C_CLS + lane] +
                  ((lane < C_CLS - 64) ? nllsum[n * C_CLS + 64 + lane] : 0.0f);
        int   q = selcnt[n * C_CLS + lane] +
                  ((lane < C_CLS - 64) ? selcnt[n * C_CLS + 64 + lane] : 0);
        #pragma unroll
        for (int o = 32; o; o >>= 1) { v += __shfl_xor(v, o); q += __shfl_xor(q, o); }
        tot += v / (float)q;
    }
    if (lane == 0) out[0] = tot;
}

extern "C" void kernel_launch(void* const* d_in, const int* in_sizes, int n_in,
                              void* d_out, int out_size, void* d_ws, size_t ws_size,
                              hipStream_t stream) {
    const float* rois       = (const float*)d_in[0];
    const float* cls_scores = (const float*)d_in[1];
    // d_in[2] = bbox_deltas: only feeds 0.0 * chosen.sum() -> never read.
    const float* gt_boxes   = (const float*)d_in[3];
    const int*   gt_clses   = (const int*)d_in[4];
    float* out = (float*)d_out;

    char* ws = (char*)d_ws;
    int*   lp      = (int*)(ws + 0);                    // N*L ints   (512 KiB)
    int*   plist   = (int*)(ws + 524288);               // N*L ints   (512 KiB)
    int*   np_arr  = (int*)(ws + 1048576);              // 32 ints
    float* nllsum  = (float*)(ws + 1048576 + 128);      // N*C floats (10 KiB)
    int*   selcnt  = (int*)(ws + 1048576 + 128 + 10240);// N*C ints   (10 KiB)

    k_match<<<N_IMG * (L_ROI / 256), 256, 0, stream>>>(rois, gt_boxes, gt_clses, lp);
    k_compact<<<N_IMG, 256, 0, stream>>>(lp, plist, np_arr);
    k_selnll<<<(N_IMG * C_CLS) / 4, 256, 0, stream>>>(cls_scores, plist, np_arr, nllsum, selcnt);
    k_final<<<1, 64, 0, stream>>>(nllsum, selcnt, out);
}